// Round 10
// baseline (912.182 us; speedup 1.0000x reference)
//
#include <hip/hip_runtime.h>
#include <cstdint>
#include <cstddef>

#define H     1024
#define LSEQ  2048
#define NHH   4
#define DKK   128
#define DVV   256
#define KDIM  512
#define VDIM  1024
#define GRR   64
#define MTOT  4096   // B*L
#define SEGL  64     // scan segment length
#define NSEG  32

enum { EPI_NONE = 0, EPI_TANH = 1, EPI_LERP = 2, EPI_DEC = 3, EPI_TANH16 = 4 };

typedef __attribute__((ext_vector_type(8))) _Float16 half8;
typedef __attribute__((ext_vector_type(4))) float f32x4;
typedef __attribute__((ext_vector_type(2))) float f32x2;

static __device__ __forceinline__ unsigned short f2h(float f) {
    _Float16 h = (_Float16)f;          // v_cvt_f16_f32, RNE
    union { _Float16 h; unsigned short u; } c;
    c.h = h;
    return c.u;
}
static __device__ __forceinline__ float h2f(unsigned short u) {
    union { unsigned short u; _Float16 h; } c;
    c.u = u;
    return (float)c.h;
}

// DPP-based partial-wave reduction step: return x + dpp_move(x, CTRL). Pure VALU.
template<int CTRL>
static __device__ __forceinline__ float dpp_add(float x) {
    int xi = __float_as_int(x);
    int mv = __builtin_amdgcn_update_dpp(0, xi, CTRL, 0xf, 0xf, true);
    return x + __int_as_float(mv);
}

// ---------------------------------------------------------------------------
// f32 VALU GEMM (thin-K lerp only): C[m][n] = sum_k A[m][k+acol]*B[n][k+bcol]
// blockIdx.z picks the mixing branch.
// ---------------------------------------------------------------------------
template<int EPI>
__global__ __launch_bounds__(256) void gemm_bt(
    const float* __restrict__ A, int lda, int acol,
    const float* __restrict__ B, int ldb, int bcol,
    float* __restrict__ Cf, unsigned short* __restrict__ C2, int ldc,
    int M, int N, int K,
    const float* __restrict__ xsrc,   // LERP epilogue source (ld = H)
    const float* __restrict__ bias)   // LERP: x_bias row
{
    if constexpr (EPI == EPI_LERP) {
        const int zz = blockIdx.z;
        acol += zz * 32;
        bcol += zz * 32;
        bias += zz * H;
        C2   += (size_t)zz * 4194304;   // fp16 slot stride
    }
    __shared__ float As[16][64];
    __shared__ float Bs[16][64];
    const int m0 = blockIdx.x * 64;
    const int n0 = blockIdx.y * 64;
    const int t  = threadIdx.x;
    const int tx = t & 15, ty = t >> 4;
    const int sm = t >> 2;
    const int sq = (t & 3) * 4;

    float acc[4][4];
#pragma unroll
    for (int i = 0; i < 4; i++)
#pragma unroll
        for (int j = 0; j < 4; j++) acc[i][j] = 0.f;

    for (int k0 = 0; k0 < K; k0 += 16) {
        {
            const int m = m0 + sm;
            const float4 av = *(const float4*)(A + (size_t)m * lda + acol + k0 + sq);
            As[sq + 0][sm] = av.x; As[sq + 1][sm] = av.y;
            As[sq + 2][sm] = av.z; As[sq + 3][sm] = av.w;
        }
        {
            const int n = n0 + sm;
            float4 bv = make_float4(0.f, 0.f, 0.f, 0.f);
            if (n < N) bv = *(const float4*)(B + (size_t)n * ldb + bcol + k0 + sq);
            Bs[sq + 0][sm] = bv.x; Bs[sq + 1][sm] = bv.y;
            Bs[sq + 2][sm] = bv.z; Bs[sq + 3][sm] = bv.w;
        }
        __syncthreads();
#pragma unroll
        for (int kk = 0; kk < 16; kk++) {
            const float4 a = *(const float4*)&As[kk][ty * 4];
            const float4 b = *(const float4*)&Bs[kk][tx * 4];
            const float av2[4] = {a.x, a.y, a.z, a.w};
            const float bv2[4] = {b.x, b.y, b.z, b.w};
#pragma unroll
            for (int i = 0; i < 4; i++)
#pragma unroll
                for (int j = 0; j < 4; j++) acc[i][j] += av2[i] * bv2[j];
        }
        __syncthreads();
    }

    const int nbase = n0 + tx * 4;
    if (nbase >= N) return;
#pragma unroll
    for (int i = 0; i < 4; i++) {
        const int m = m0 + ty * 4 + i;
        float4 r = make_float4(acc[i][0], acc[i][1], acc[i][2], acc[i][3]);
        if constexpr (EPI == EPI_LERP) {
            const float4 bb = *(const float4*)(bias + nbase);
            const float4 xv = *(const float4*)(xsrc + (size_t)m * H + nbase);
            float4 pv = make_float4(0.f, 0.f, 0.f, 0.f);
            if ((m & (LSEQ - 1)) != 0)
                pv = *(const float4*)(xsrc + (size_t)(m - 1) * H + nbase);
            r.x = xv.x + (pv.x - xv.x) * (r.x + bb.x);
            r.y = xv.y + (pv.y - xv.y) * (r.y + bb.y);
            r.z = xv.z + (pv.z - xv.z) * (r.z + bb.z);
            r.w = xv.w + (pv.w - xv.w) * (r.w + bb.w);
        }
        if (Cf) *(float4*)(Cf + (size_t)m * ldc + nbase) = r;
        if (C2) {
            ushort4 p;
            p.x = f2h(r.x); p.y = f2h(r.y); p.z = f2h(r.z); p.w = f2h(r.w);
            *(ushort4*)(C2 + (size_t)m * ldc + nbase) = p;
        }
    }
}

// ---------------------------------------------------------------------------
// fp16 MFMA GEMM (m97 structure): C[m][n] = sum_k A[m][k] * B[n][k].
// ---------------------------------------------------------------------------
template<int EPI>
__global__ __launch_bounds__(256) void gemm_mfma_bt(
    const unsigned short* __restrict__ A,
    const unsigned short* __restrict__ A2, int nsplit, int lda,
    const unsigned short* __restrict__ B, int ldb,
    float* __restrict__ C, unsigned short* __restrict__ Ch, int ldc, int K,
    const float* __restrict__ bias)
{
    __shared__ __align__(16) unsigned short As[128 * 32];
    __shared__ __align__(16) unsigned short Bs[128 * 32];
    const int t    = threadIdx.x;
    const int w    = t >> 6;
    const int lane = t & 63;
    const int m0 = blockIdx.x * 128;
    const int n0 = blockIdx.y * 128;
    const unsigned short* Au = (n0 < nsplit) ? A : A2;
    const int mw = (w & 1) * 64;
    const int nw = (w >> 1) * 64;
    const int l15 = lane & 15;
    const int q4  = lane >> 4;

    f32x4 acc[4][4];
#pragma unroll
    for (int i = 0; i < 4; i++)
#pragma unroll
        for (int j = 0; j < 4; j++) {
            f32x4 z = {0.f, 0.f, 0.f, 0.f};
            acc[i][j] = z;
        }

    for (int k0 = 0; k0 < K; k0 += 32) {
        __syncthreads();
#pragma unroll
        for (int jj = 0; jj < 2; jj++) {
            const int c   = w * 128 + jj * 64 + lane;
            const int row = c >> 2;
            const int col = (c & 3) * 8;
            __builtin_amdgcn_global_load_lds(
                (const __attribute__((address_space(1))) void*)(Au + (size_t)(m0 + row) * lda + k0 + col),
                (__attribute__((address_space(3))) void*)((char*)As + (w * 128 + jj * 64) * 16),
                16, 0, 0);
            __builtin_amdgcn_global_load_lds(
                (const __attribute__((address_space(1))) void*)(B + (size_t)(n0 + row) * ldb + k0 + col),
                (__attribute__((address_space(3))) void*)((char*)Bs + (w * 128 + jj * 64) * 16),
                16, 0, 0);
        }
        __syncthreads();

        half8 a[4], b[4];
#pragma unroll
        for (int i = 0; i < 4; i++)
            a[i] = *(const half8*)(As + (mw + i * 16 + l15) * 32 + q4 * 8);
#pragma unroll
        for (int j = 0; j < 4; j++)
            b[j] = *(const half8*)(Bs + (nw + j * 16 + l15) * 32 + q4 * 8);
#pragma unroll
        for (int i = 0; i < 4; i++)
#pragma unroll
            for (int j = 0; j < 4; j++)
                acc[i][j] = __builtin_amdgcn_mfma_f32_16x16x32_f16(a[i], b[j], acc[i][j], 0, 0, 0);
    }

#pragma unroll
    for (int i = 0; i < 4; i++) {
        const int m_base = m0 + mw + i * 16 + q4 * 4;
#pragma unroll
        for (int j = 0; j < 4; j++) {
            const int n = n0 + nw + j * 16 + l15;
#pragma unroll
            for (int r = 0; r < 4; r++) {
                float val = acc[i][j][r];
                if constexpr (EPI == EPI_TANH) {
                    C[(size_t)(m_base + r) * ldc + n] = tanhf(val);
                } else if constexpr (EPI == EPI_TANH16) {
                    Ch[(size_t)(m_base + r) * ldc + n] = f2h(tanhf(val));
                } else {
                    C[(size_t)(m_base + r) * ldc + n] = val;
                }
            }
        }
    }
}

// ---------------------------------------------------------------------------
// Mega MFMA launch: vg (blocks 0..511) + rk (512..767) + dec (768..895).
// Same body as gemm_mfma_bt, per-block job select. dec: K=64, EPI_DEC.
// ---------------------------------------------------------------------------
__global__ __launch_bounds__(256) void gemm_mfma_mega(
    const unsigned short* __restrict__ insb,
    const unsigned short* __restrict__ wlow16,
    const unsigned short* __restrict__ Ww2p,
    const unsigned short* __restrict__ Wrb,
    const unsigned short* __restrict__ Wvb,
    float* __restrict__ rkB, float* __restrict__ vgB, float* __restrict__ decB,
    const float* __restrict__ bw2)
{
    const int bx = blockIdx.x;
    const unsigned short *A, *A2, *B;
    float* C;
    int nsplit, lda, ldb, ldc, K, epi, local;
    if (bx < 512) {          // vg = [v|g], N=2048
        local = bx;
        A  = insb + 3ul * 4194304; A2 = insb + 4ul * 4194304;
        nsplit = 1024; lda = 1024; B = Wvb; ldb = 1024;
        C = vgB; ldc = 2048; K = 1024; epi = 0;
    } else if (bx < 768) {   // rk = [r|k], N=1024
        local = bx - 512;
        A  = insb;                 A2 = insb + 2ul * 4194304;
        nsplit = 512; lda = 1024; B = Wrb; ldb = 1024;
        C = rkB; ldc = 1024; K = 1024; epi = 0;
    } else {                 // dec, N=512, K=64
        local = bx - 768;
        A = wlow16; A2 = wlow16;
        nsplit = 1 << 30; lda = 128; B = Ww2p; ldb = 64;
        C = decB; ldc = 512; K = 64; epi = 1;
    }
    const int m0 = (local & 31) * 128;
    const int n0 = (local >> 5) * 128;

    __shared__ __align__(16) unsigned short As[128 * 32];
    __shared__ __align__(16) unsigned short Bs[128 * 32];
    const int t    = threadIdx.x;
    const int w    = t >> 6;
    const int lane = t & 63;
    const unsigned short* Au = (n0 < nsplit) ? A : A2;
    const int mw = (w & 1) * 64;
    const int nw = (w >> 1) * 64;
    const int l15 = lane & 15;
    const int q4  = lane >> 4;

    f32x4 acc[4][4];
#pragma unroll
    for (int i = 0; i < 4; i++)
#pragma unroll
        for (int j = 0; j < 4; j++) {
            f32x4 z = {0.f, 0.f, 0.f, 0.f};
            acc[i][j] = z;
        }

    for (int k0 = 0; k0 < K; k0 += 32) {
        __syncthreads();
#pragma unroll
        for (int jj = 0; jj < 2; jj++) {
            const int c   = w * 128 + jj * 64 + lane;
            const int row = c >> 2;
            const int col = (c & 3) * 8;
            __builtin_amdgcn_global_load_lds(
                (const __attribute__((address_space(1))) void*)(Au + (size_t)(m0 + row) * lda + k0 + col),
                (__attribute__((address_space(3))) void*)((char*)As + (w * 128 + jj * 64) * 16),
                16, 0, 0);
            __builtin_amdgcn_global_load_lds(
                (const __attribute__((address_space(1))) void*)(B + (size_t)(n0 + row) * ldb + k0 + col),
                (__attribute__((address_space(3))) void*)((char*)Bs + (w * 128 + jj * 64) * 16),
                16, 0, 0);
        }
        __syncthreads();

        half8 a[4], b[4];
#pragma unroll
        for (int i = 0; i < 4; i++)
            a[i] = *(const half8*)(As + (mw + i * 16 + l15) * 32 + q4 * 8);
#pragma unroll
        for (int j = 0; j < 4; j++)
            b[j] = *(const half8*)(Bs + (nw + j * 16 + l15) * 32 + q4 * 8);
#pragma unroll
        for (int i = 0; i < 4; i++)
#pragma unroll
            for (int j = 0; j < 4; j++)
                acc[i][j] = __builtin_amdgcn_mfma_f32_16x16x32_f16(a[i], b[j], acc[i][j], 0, 0, 0);
    }

#pragma unroll
    for (int i = 0; i < 4; i++) {
        const int m_base = m0 + mw + i * 16 + q4 * 4;
#pragma unroll
        for (int j = 0; j < 4; j++) {
            const int n = n0 + nw + j * 16 + l15;
#pragma unroll
            for (int r = 0; r < 4; r++) {
                float val = acc[i][j][r];
                if (epi) val = expf(-expf(val + bw2[n]));
                C[(size_t)(m_base + r) * ldc + n] = val;
            }
        }
    }
}

// ---------------------------------------------------------------------------
// Scan correction (M=64 per segment): o[seg,bh][m,n] += rt16[m,:]·Sentry[n,:]
// Tile 64x256, K=128. 248 blocks: z = (seg-1)*8 + bh, seg 1..31.
// 4 waves: wave w covers n = w*64..+63, m = 0..63.
// ---------------------------------------------------------------------------
__global__ __launch_bounds__(256) void gemm_mfma_corr(
    const unsigned short* __restrict__ rt16,
    const unsigned short* __restrict__ SentryT16,
    float* __restrict__ o)
{
    const int z   = blockIdx.x;
    const int seg = (z >> 3) + 1;
    const int bh  = z & 7;
    const int b   = bh >> 2, h = bh & 3;
    const unsigned short* A = rt16 + ((size_t)b * LSEQ + seg * SEGL) * KDIM + h * DKK;
    const unsigned short* B = SentryT16 + (size_t)(seg * 8 + bh) * 32768;
    float* C = o + ((size_t)b * LSEQ + seg * SEGL) * VDIM + h * DVV;

    __shared__ __align__(16) unsigned short As[64 * 32];
    __shared__ __align__(16) unsigned short Bs[256 * 32];
    const int t    = threadIdx.x;
    const int w    = t >> 6;
    const int lane = t & 63;
    const int l15 = lane & 15;
    const int q4  = lane >> 4;

    f32x4 acc[4][4];
#pragma unroll
    for (int i = 0; i < 4; i++)
#pragma unroll
        for (int j = 0; j < 4; j++) {
            f32x4 zz = {0.f, 0.f, 0.f, 0.f};
            acc[i][j] = zz;
        }

    for (int k0 = 0; k0 < 128; k0 += 32) {
        __syncthreads();
        {   // A: 64 rows x 32 halves = 256 chunks, 1 per thread
            const int c   = w * 64 + lane;
            const int row = c >> 2;
            const int col = (c & 3) * 8;
            __builtin_amdgcn_global_load_lds(
                (const __attribute__((address_space(1))) void*)(A + (size_t)row * KDIM + k0 + col),
                (__attribute__((address_space(3))) void*)((char*)As + (w * 64) * 16),
                16, 0, 0);
        }
#pragma unroll
        for (int jj = 0; jj < 4; jj++) {   // B: 256 rows x 32 halves = 1024 chunks
            const int c   = jj * 256 + w * 64 + lane;
            const int row = c >> 2;
            const int col = (c & 3) * 8;
            __builtin_amdgcn_global_load_lds(
                (const __attribute__((address_space(1))) void*)(B + (size_t)row * 128 + k0 + col),
                (__attribute__((address_space(3))) void*)((char*)Bs + (jj * 256 + w * 64) * 16),
                16, 0, 0);
        }
        __syncthreads();

        half8 a[4], bb[4];
#pragma unroll
        for (int i = 0; i < 4; i++)
            a[i] = *(const half8*)(As + (i * 16 + l15) * 32 + q4 * 8);
#pragma unroll
        for (int j = 0; j < 4; j++)
            bb[j] = *(const half8*)(Bs + (w * 64 + j * 16 + l15) * 32 + q4 * 8);
#pragma unroll
        for (int i = 0; i < 4; i++)
#pragma unroll
            for (int j = 0; j < 4; j++)
                acc[i][j] = __builtin_amdgcn_mfma_f32_16x16x32_f16(a[i], bb[j], acc[i][j], 0, 0, 0);
    }

#pragma unroll
    for (int i = 0; i < 4; i++) {
        const int m_base = i * 16 + q4 * 4;
#pragma unroll
        for (int j = 0; j < 4; j++) {
            const int n = w * 64 + j * 16 + l15;
#pragma unroll
            for (int rr = 0; rr < 4; rr++)
                C[(size_t)(m_base + rr) * VDIM + n] += acc[i][j][rr];
        }
    }
}

// ---------------------------------------------------------------------------
// prep: fp16 packs fused with xl = x + (shift(x)-x)*mu_x.
// ---------------------------------------------------------------------------
__global__ __launch_bounds__(256) void prep_kernel(
    const float* __restrict__ Wr, const float* __restrict__ Wk,
    const float* __restrict__ Wv, const float* __restrict__ Wg,
    const float* __restrict__ Wo, const float* __restrict__ Wx1,
    const float* __restrict__ Ww1, const float* __restrict__ Ww2,
    unsigned short* __restrict__ Wb, unsigned short* __restrict__ Wx1p,
    unsigned short* __restrict__ Ww1p, unsigned short* __restrict__ Ww2p,
    const float* __restrict__ x, const float* __restrict__ mux,
    unsigned short* __restrict__ xl16)
{
    const int bx = blockIdx.x;
    if (bx < 4512) {
        const int q = bx * 256 + threadIdx.x;
        float4 v = make_float4(0.f, 0.f, 0.f, 0.f);
        unsigned short* dst;
        if (q < 1048576) {
            const int i4 = q * 4;
            const float* src; int off;
            if      (i4 <  524288) { src = Wr; off = i4; }
            else if (i4 < 1048576) { src = Wk; off = i4 -  524288; }
            else if (i4 < 2097152) { src = Wv; off = i4 - 1048576; }
            else if (i4 < 3145728) { src = Wg; off = i4 - 2097152; }
            else                   { src = Wo; off = i4 - 3145728; }
            v = *(const float4*)(src + off);
            dst = Wb + i4;
        } else if (q < 1114112) {
            const int e = (q - 1048576) * 4;
            const int row = e >> 10;
            if (row < 160) v = *(const float4*)(Wx1 + (size_t)row * H + (e & 1023));
            dst = Wx1p + e;
        } else if (q < 1146880) {
            const int e = (q - 1114112) * 4;
            const int row = e >> 10;
            if (row < 64) v = *(const float4*)(Ww1 + (size_t)row * H + (e & 1023));
            dst = Ww1p + e;
        } else {
            const int e = (q - 1146880) * 4;
            v = *(const float4*)(Ww2 + e);
            dst = Ww2p + e;
        }
        ushort4 o4;
        o4.x = f2h(v.x); o4.y = f2h(v.y); o4.z = f2h(v.z); o4.w = f2h(v.w);
        *(ushort4*)dst = o4;
    } else {
        const int m = bx - 4512;
        const int c = threadIdx.x * 4;
        const float4 xv = *(const float4*)(x + (size_t)m * H + c);
        float4 pv = make_float4(0.f, 0.f, 0.f, 0.f);
        if ((m & (LSEQ - 1)) != 0)
            pv = *(const float4*)(x + (size_t)(m - 1) * H + c);
        const float4 mv = *(const float4*)(mux + c);
        ushort4 p;
        p.x = f2h(xv.x + (pv.x - xv.x) * mv.x);
        p.y = f2h(xv.y + (pv.y - xv.y) * mv.y);
        p.z = f2h(xv.z + (pv.z - xv.z) * mv.z);
        p.w = f2h(xv.w + (pv.w - xv.w) * mv.w);
        *(ushort4*)(xl16 + (size_t)m * H + c) = p;
    }
}

// ---------------------------------------------------------------------------
// Scan pass 1 v7: 32 segments -> 2048 blocks = 8 blocks/CU (launch_bounds 8).
// 4 v-cols per thread, packed-f32 math, XCD swizzle, DPP reduce.
// Segment-final state stored fp16 (Sloc16).
// ---------------------------------------------------------------------------
__global__ __launch_bounds__(256, 8) void scan_pass1(
    const float* __restrict__ rk, const float* __restrict__ vg,
    const float* __restrict__ dec, const float* __restrict__ bonus,
    float* __restrict__ o, unsigned short* __restrict__ rt16,
    unsigned short* __restrict__ Sloc16, float* __restrict__ Dtot)
{
    const int bh  = blockIdx.x & 7;
    const int vc  = (blockIdx.x >> 3) & 7;
    const int seg = blockIdx.x >> 6;           // 0..31
    const int b   = bh >> 2;
    const int h   = bh & 3;
    const int t   = threadIdx.x;
    const int kg  = t & 31;
    const int vl  = t >> 5;
    const bool wlead = (vc == 0) && (vl == 0);

    f32x2 S2[4][2];
    float D[4] = {1.f, 1.f, 1.f, 1.f}, u[4];
#pragma unroll
    for (int j = 0; j < 4; j++) {
        u[j] = bonus[h * DKK + kg * 4 + j];
        f32x2 z = {0.f, 0.f};
        S2[j][0] = z; S2[j][1] = z;
    }

    const size_t row0 = (size_t)b * LSEQ + (size_t)seg * SEGL;
    const float* rp = rk  + row0 * 1024 + h * DKK + kg * 4;   // k at rp+512
    const float* dp = dec + row0 * 512  + h * DKK + kg * 4;
    const float* vp = vg  + row0 * 2048 + h * DVV + vc * 32 + vl * 4;
    float*       op = o   + row0 * 1024 + h * DVV + vc * 32 + vl * 4;
    unsigned short* rt = rt16 + row0 * 512 + h * DKK + kg * 4;

    float4 cr = *(const float4*)rp;
    float4 ck = *(const float4*)(rp + 512);
    float4 cd = *(const float4*)dp;
    float4 cv = *(const float4*)vp;
    rp += 1024; dp += 512; vp += 2048;

    for (int t0 = 0; t0 < SEGL; ++t0) {
        const float4 nr = *(const float4*)rp;          // last iter reads slack row
        const float4 nk = *(const float4*)(rp + 512);
        const float4 nd = *(const float4*)dp;
        const float4 nv = *(const float4*)vp;
        rp += 1024; dp += 512; vp += 2048;

        if (wlead) {   // r~ = r * D (exclusive cumprod), fp16
            ushort4 p;
            p.x = f2h(cr.x * D[0]); p.y = f2h(cr.y * D[1]);
            p.z = f2h(cr.z * D[2]); p.w = f2h(cr.w * D[3]);
            *(ushort4*)rt = p;
        }
        rt += 512;

        const float ra[4] = {cr.x, cr.y, cr.z, cr.w};
        const float ka[4] = {ck.x, ck.y, ck.z, ck.w};
        const float da[4] = {cd.x, cd.y, cd.z, cd.w};
        f32x2 va2[2];
        va2[0].x = cv.x; va2[0].y = cv.y;
        va2[1].x = cv.z; va2[1].y = cv.w;
        f32x2 part2[2];
        part2[0] = (f32x2){0.f, 0.f};
        part2[1] = (f32x2){0.f, 0.f};
#pragma unroll
        for (int j = 0; j < 4; j++) {
#pragma unroll
            for (int p = 0; p < 2; p++) {
                const f32x2 kv2 = va2[p] * ka[j];
                part2[p] += ra[j] * (S2[j][p] + u[j] * kv2);
                S2[j][p] = da[j] * S2[j][p] + kv2;
            }
            D[j] *= da[j];
        }
        float part[4] = {part2[0].x, part2[0].y, part2[1].x, part2[1].y};
#pragma unroll
        for (int jj = 0; jj < 4; jj++) {
            part[jj] = dpp_add<0xB1>(part[jj]);
            part[jj] = dpp_add<0x4E>(part[jj]);
            part[jj] = dpp_add<0x141>(part[jj]);
            part[jj] = dpp_add<0x140>(part[jj]);
            part[jj] = dpp_add<0x142>(part[jj]);
        }
        if (kg == 31) {
            float4 res = make_float4(part[0], part[1], part[2], part[3]);
            *(float4*)op = res;
        }
        op += 1024;
        cr = nr; ck = nk; cd = nd; cv = nv;
    }

    {   // segment-final state [k][vcol] (fp16) + total decay
        unsigned short* sl16 = Sloc16 + (size_t)(seg * 8 + bh) * 32768
                               + (size_t)(kg * 4) * 256 + vc * 32 + vl * 4;
#pragma unroll
        for (int j = 0; j < 4; j++) {
            ushort4 sv;
            sv.x = f2h(S2[j][0].x); sv.y = f2h(S2[j][0].y);
            sv.z = f2h(S2[j][1].x); sv.w = f2h(S2[j][1].y);
            *(ushort4*)(sl16 + j * 256) = sv;
        }
        if (wlead) {
            float* dt = Dtot + (seg * 8 + bh) * 128 + kg * 4;
#pragma unroll
            for (int j = 0; j < 4; j++) dt[j] = D[j];
        }
    }
}

// ---------------------------------------------------------------------------
// Scan pass 2: propagate entry states across 32 segments; Sentry^T as fp16.
// ---------------------------------------------------------------------------
__global__ __launch_bounds__(256) void scan_pass2(
    const unsigned short* __restrict__ Sloc16, const float* __restrict__ Dtot,
    unsigned short* __restrict__ SentryT16)
{
    const int vc = blockIdx.x & 31;
    const int bh = blockIdx.x >> 5;
    const int t  = threadIdx.x;
    const int kg = t & 31;
    const int vl = t >> 5;

    float S[4] = {0.f, 0.f, 0.f, 0.f};
    for (int p = 0; p < NSEG; p++) {
        unsigned short* st = SentryT16 + (size_t)(p * 8 + bh) * 32768
                             + (size_t)(vc * 8 + vl) * 128 + kg * 4;
        ushort4 pk;
        pk.x = f2h(S[0]); pk.y = f2h(S[1]); pk.z = f2h(S[2]); pk.w = f2h(S[3]);
        *(ushort4*)st = pk;
        if (p < NSEG - 1) {
            const unsigned short* sl = Sloc16 + (size_t)(p * 8 + bh) * 32768
                                       + (size_t)(kg * 4) * 256 + vc * 8 + vl;
            const float* dt = Dtot + (p * 8 + bh) * 128 + kg * 4;
#pragma unroll
            for (int j = 0; j < 4; j++) S[j] = dt[j] * S[j] + h2f(sl[j * 256]);
        }
    }
}

// ---------------------------------------------------------------------------
// Per-head LayerNorm + swish gate -> fp16. g lives in the fused vg buffer.
// ---------------------------------------------------------------------------
__global__ __launch_bounds__(256) void ln_gate_kernel(
    const float* __restrict__ o, const float* __restrict__ vg,
    const float* __restrict__ lnw, const float* __restrict__ lnb,
    unsigned short* __restrict__ out)
{
    const int m    = blockIdx.x;
    const int t    = threadIdx.x;
    const int h    = t >> 6;
    const int lane = t & 63;
    const size_t obase = (size_t)m * VDIM + (size_t)h * DVV + lane * 4;
    const size_t gbase = (size_t)m * 2048 + 1024 + (size_t)h * DVV + lane * 4;
    const float4 ov = *(const float4*)(o + obase);
    float sum = ov.x + ov.y + ov.z + ov.w;
    float sq  = ov.x * ov.x + ov.y * ov.y + ov.z * ov.z + ov.w * ov.w;
#pragma unroll
    for (int off = 1; off < 64; off <<= 1) {
        sum += __shfl_xor(sum, off);
        sq  += __shfl_xor(sq, off);
    }
    const float mean = sum * (1.f / DVV);
    const float var  = sq * (1.f / DVV) - mean * mean;
    const float rstd = rsqrtf(var + 1e-5f);
    const float4 gv = *(const float4*)(vg + gbase);
    const float4 wv = *(const float4*)(lnw + lane * 4);
    const float4 bv = *(const float4*)(lnb + lane * 4);
    float4 res;
    res.x = ((ov.x - mean) * rstd * wv.x + bv.x) * (gv.x / (1.f + expf(-gv.x)));
    res.y = ((ov.y - mean) * rstd * wv.y + bv.y) * (gv.y / (1.f + expf(-gv.y)));
    res.z = ((ov.z - mean) * rstd * wv.z + bv.z) * (gv.z / (1.f + expf(-gv.z)));
    res.w = ((ov.w - mean) * rstd * wv.w + bv.w) * (gv.w / (1.f + expf(-gv.w)));
    ushort4 p;
    p.x = f2h(res.x); p.y = f2h(res.y); p.z = f2h(res.z); p.w = f2h(res.w);
    *(ushort4*)(out + obase) = p;
}

extern "C" void kernel_launch(void* const* d_in, const int* in_sizes, int n_in,
                              void* d_out, int out_size, void* d_ws, size_t ws_size,
                              hipStream_t stream)
{
    const float* x     = (const float*)d_in[0];
    const float* mu_x  = (const float*)d_in[1];
    const float* Wx1   = (const float*)d_in[2];
    const float* Wx2   = (const float*)d_in[3];
    const float* xb    = (const float*)d_in[4];
    const float* Wr    = (const float*)d_in[5];
    const float* Wk    = (const float*)d_in[6];
    const float* Wv    = (const float*)d_in[7];
    const float* Wg    = (const float*)d_in[8];
    const float* Ww1   = (const float*)d_in[9];
    const float* Ww2   = (const float*)d_in[10];
    const float* bw2   = (const float*)d_in[11];
    const float* bonus = (const float*)d_in[12];
    const float* lnw   = (const float*)d_in[13];
    const float* lnb   = (const float*)d_in[14];
    const float* Wo    = (const float*)d_in[15];
    float* out = (float*)d_out;
    (void)in_sizes; (void)n_in; (void)out_size; (void)ws_size;

    float* ws = (float*)d_ws;
    // layout (f32 word offsets):
    unsigned short* Wx1p = (unsigned short*)(ws + 0);         // 131072 w
    unsigned short* Ww1p = (unsigned short*)(ws + 131072);    // 65536 w
    unsigned short* Ww2p = (unsigned short*)(ws + 196608);    // 16384 w
    unsigned short* Wb   = (unsigned short*)(ws + 212992);    // 2097152 w
    float* xp     = ws + 2310144;                             // 1048576 w
    unsigned short* wlow16 = (unsigned short*)(ws + 3358720); // 262144 w
    float* insB   = ws + 3620864;                             // 10485760 w (5 slots)
    float* rkB    = ws + 14106624;                            // 4195328 w (4097x1024)
    float* vgB    = ws + 18301952;                            // 8390656 w (4097x2048)
    float* decB   = ws + 26692608;                            // 2097664 w (4097x512)
    // total 28790272 words (~115 MB)

    unsigned short* insb = (unsigned short*)insB;
    unsigned short* Wrb  = Wb;                                // [Wr;Wk] rows 0..1023
    unsigned short* Wvb  = Wb + 1048576;                      // [Wv;Wg] rows 0..2047
    unsigned short* Wob  = Wb + 3145728;
    unsigned short* xl16 = (unsigned short*)rkB;              // dead after xp GEMM
    // scan-time aliases (stream-ordered, sizes audited):
    float*          o       = insB;                                   // slots 0,1 (consumed)
    unsigned short* rt16    = insb + 2ul * 4194304;                   // slot 2 (consumed)
    unsigned short* Sloc16  = insb + 3ul * 4194304;                   // slots 3+4: 8388608 h exact
    float*          Dtot    = (float*)wlow16;                         // 32768 w <= 262144
    unsigned short* SentryT16 = (unsigned short*)rkB;                 // 8388608 h <= 8390656 h
    unsigned short* gatedb  = (unsigned short*)(insB + 3ul * 2097152);// slot 3 (Sloc dead after pass2)

    dim3 blk(256);

    prep_kernel<<<dim3(8608), blk, 0, stream>>>(Wr, Wk, Wv, Wg, Wo, Wx1, Ww1, Ww2,
                                                Wb, Wx1p, Ww1p, Ww2p, x, mu_x, xl16);

    // xp = tanh(xl @ Wx1p^T)  [4096 x 256 f32, cols 160.. zero]
    gemm_mfma_bt<EPI_TANH><<<dim3(32, 2), blk, 0, stream>>>(
        xl16, xl16, 1 << 30, H, Wx1p, H, xp, nullptr, 256, H, nullptr);

    // fused thin-K: in_n = x + delta*(xp_n @ Wx2_n^T + x_bias_n) -> fp16 slot n
    gemm_bt<EPI_LERP><<<dim3(64, 16, 5), blk, 0, stream>>>(
        xp, 256, 0, Wx2, 160, 0, nullptr, insb, H, MTOT, H, 32, x, xb);

    // wlow16 = tanh(in_w16 @ Ww1p^T) fp16  [4096 x 128, cols 64.. zero]
    gemm_mfma_bt<EPI_TANH16><<<dim3(32, 1), blk, 0, stream>>>(
        insb + 1ul * 4194304, insb + 1ul * 4194304, 1 << 30, H, Ww1p, H,
        nullptr, wlow16, 128, H, nullptr);

    // mega: vg = [v|g] + rk = [r|k] + dec in one launch
    gemm_mfma_mega<<<dim3(896), blk, 0, stream>>>(
        insb, wlow16, Ww2p, Wrb, Wvb, rkB, vgB, decB, bw2);

    // segmented RWKV scan (32 segments, XCD-swizzled)
    scan_pass1<<<dim3(2048), blk, 0, stream>>>(rkB, vgB, decB, bonus, o, rt16, Sloc16, Dtot);
    scan_pass2<<<dim3(256), blk, 0, stream>>>(Sloc16, Dtot, SentryT16);
    gemm_mfma_corr<<<dim3(248), blk, 0, stream>>>(rt16, SentryT16, o);

    // per-head LN + swish gate -> fp16 gated
    ln_gate_kernel<<<dim3(4096), blk, 0, stream>>>(o, vgB, lnw, lnb, gatedb);

    // out = gated @ Wo^T
    gemm_mfma_bt<EPI_NONE><<<dim3(32, 8), blk, 0, stream>>>(
        gatedb, gatedb, 1 << 30, VDIM, Wob, VDIM, out, nullptr, H, VDIM, nullptr);
}